// Round 7
// baseline (98.150 us; speedup 1.0000x reference)
//
#include <hip/hip_runtime.h>

typedef float f4 __attribute__((ext_vector_type(4)));

#define BB 32
#define CC 512
#define LL 4096
#define NB 16
#define EPSF 1e-8f

// ---------------- fused main kernel: pipelined, ONE read of x -------------
// grid = 32 b x 16 chunks = 512 blocks (2/CU). Wave w owns channels
// c0+8w..8w+7. Per row: [arrival: ss-FMA + row-sum + ds_write (gv-free)] ->
// [issue NEXT row's loads] -> [shuffle-reduce -> gv] -> [dot-FMA from LDS].
// The next row's loads are in flight during the reduce+dot phase, closing
// the R4/R5 bubble where the wave had nothing outstanding. Wave-private
// LDS buffers -> no barriers in the hot loop.
__global__ __launch_bounds__(256, 2)
void k_main(const float* __restrict__ x, float* __restrict__ g,
            f4* __restrict__ pd4, f4* __restrict__ ps4) {
    __shared__ f4 buf[4][1024];              // 64 KB, wave-private 16 KB each
    const int tid = threadIdx.x;
    const int w = tid >> 6, lane = tid & 63;
    const int b  = blockIdx.x >> 4;
    const int c0 = (blockIdx.x & 15) * 32;

    f4 dA[16], sA[16];
#pragma unroll
    for (int i = 0; i < 16; ++i) { dA[i] = (f4)0.f; sA[i] = (f4)0.f; }

    const f4* base = (const f4*)(x + ((size_t)b * CC + c0 + w * 8) * LL);
    f4* wb = buf[w];

    f4 v[16];
#pragma unroll
    for (int i = 0; i < 16; ++i) v[i] = base[i * 64 + lane];   // row 0

    for (int cc = 0; cc < 8; ++cc) {
        // arrival phase: everything that doesn't need gv
        float s = 0.f;
#pragma unroll
        for (int i = 0; i < 16; ++i) {
            wb[i * 64 + lane] = v[i];
#pragma unroll
            for (int k = 0; k < 4; ++k)
                sA[i][k] = fmaf(v[i][k], v[i][k], sA[i][k]);
            s += (v[i][0] + v[i][1]) + (v[i][2] + v[i][3]);
        }
        // issue next row's loads NOW (row is safe in LDS; v regs reusable)
        if (cc < 7) {
            const f4* nr = base + (size_t)(cc + 1) * 1024;
#pragma unroll
            for (int i = 0; i < 16; ++i) v[i] = nr[i * 64 + lane];
        }
        __builtin_amdgcn_sched_barrier(0);   // keep loads above the dot phase
        // reduce -> gv
#pragma unroll
        for (int off = 32; off; off >>= 1) s += __shfl_down(s, off, 64);
        s = __shfl(s, 0, 64);
        const float gv = s * (1.0f / LL);
        if (lane == 0) g[b * CC + c0 + w * 8 + cc] = gv;
        // dot phase from LDS (ds_read_b128, wave-private, conflict-free)
#pragma unroll
        for (int i = 0; i < 16; ++i) {
            f4 f = wb[i * 64 + lane];
#pragma unroll
            for (int k = 0; k < 4; ++k)
                dA[i][k] = fmaf(f[k], gv, dA[i][k]);
        }
    }
    __syncthreads();
    // 4-step wave combine reusing buf (ascending w keeps c-summation order)
    f4* ldsD = &buf[0][0];                   // 1024 f4
    f4* ldsS = &buf[2][0];                   // 1024 f4
    for (int ww = 0; ww < 4; ++ww) {
        if (w == ww) {
#pragma unroll
            for (int i = 0; i < 16; ++i) {
                const int idx = i * 64 + lane;
                if (ww == 0) { ldsD[idx] = dA[i];  ldsS[idx] = sA[i]; }
                else         { ldsD[idx] += dA[i]; ldsS[idx] += sA[i]; }
            }
        }
        __syncthreads();
    }
#pragma unroll
    for (int j = 0; j < 4; ++j) {
        pd4[(size_t)blockIdx.x * 1024 + j * 256 + tid] = ldsD[j * 256 + tid];
        ps4[(size_t)blockIdx.x * 1024 + j * 256 + tid] = ldsS[j * 256 + tid];
    }
}

// ---------------- reduce: fold chunk partials -> cos + min/max partials ----
// 512 blocks x 256 threads (8 waves/CU). Block owns 64 quads; wave w folds
// chunks 4w..4w+3, LDS combine, wave 0 finishes cos + min/max.
__global__ __launch_bounds__(256, 8)
void k_reduce(const float* __restrict__ g,
              const f4* __restrict__ pd4, const f4* __restrict__ ps4,
              f4* __restrict__ cosv4,
              float* __restrict__ pmin, float* __restrict__ pmax) {
    const int tid = threadIdx.x;
    const int w = tid >> 6, lane = tid & 63;
    const int b = blockIdx.x >> 4;
    const int sl = (blockIdx.x & 15) * 64 + lane;   // quad slot within b

    f4 pdv = (f4)0.f, psv = (f4)0.f;
    const size_t cb = (size_t)b * 16;
#pragma unroll
    for (int c = 0; c < 4; ++c) {
        const int ch = 4 * w + c;
        pdv += pd4[((cb + ch) << 10) + sl];
        psv += ps4[((cb + ch) << 10) + sl];
    }
    __shared__ f4 sD[4][64], sS[4][64];
    sD[w][lane] = pdv;
    sS[w][lane] = psv;

    // per-wave redundant gn (L2-hot, overlaps with partial loads)
    const f4* g4p = (const f4*)(g + b * CC);
    f4 ga = g4p[lane], gb2 = g4p[64 + lane];
    float sq = 0.f;
#pragma unroll
    for (int k = 0; k < 4; ++k) sq = fmaf(ga[k], ga[k], fmaf(gb2[k], gb2[k], sq));
#pragma unroll
    for (int off = 32; off; off >>= 1) sq += __shfl_down(sq, off, 64);
    const float gn = sqrtf(__shfl(sq, 0, 64));

    __syncthreads();
    if (tid < 64) {
        f4 d = ((sD[0][lane] + sD[1][lane]) + sD[2][lane]) + sD[3][lane];
        f4 ssum = ((sS[0][lane] + sS[1][lane]) + sS[2][lane]) + sS[3][lane];
        f4 cs;
#pragma unroll
        for (int k = 0; k < 4; ++k)
            cs[k] = d[k] / fmaxf(sqrtf(ssum[k]) * gn, EPSF);
        cosv4[(size_t)b * 1024 + sl] = cs;

        float mn = fminf(fminf(cs[0], cs[1]), fminf(cs[2], cs[3]));
        float mx = fmaxf(fmaxf(cs[0], cs[1]), fmaxf(cs[2], cs[3]));
#pragma unroll
        for (int off = 32; off; off >>= 1) {
            mn = fminf(mn, __shfl_down(mn, off, 64));
            mx = fmaxf(mx, __shfl_down(mx, off, 64));
        }
        if (lane == 0) { pmin[blockIdx.x] = mn; pmax[blockIdx.x] = mx; }
    }
}

// ---------------- histogram per b, normalize, broadcast ----------------
__global__ void k_hist(const f4* __restrict__ cosv4,
                       const float* __restrict__ pmin, const float* __restrict__ pmax,
                       float* __restrict__ out) {
    const int b = blockIdx.x;
    const int wave = threadIdx.x >> 6, lane = threadIdx.x & 63;

    float mn = fminf(pmin[threadIdx.x], pmin[threadIdx.x + 256]);   // 512 partials
    float mx = fmaxf(pmax[threadIdx.x], pmax[threadIdx.x + 256]);
#pragma unroll
    for (int off = 32; off; off >>= 1) {
        mn = fminf(mn, __shfl_down(mn, off, 64));
        mx = fmaxf(mx, __shfl_down(mx, off, 64));
    }
    __shared__ float smn[4], smx[4];
    if (lane == 0) { smn[wave] = mn; smx[wave] = mx; }
    __syncthreads();
    mn = fminf(fminf(smn[0], smn[1]), fminf(smn[2], smn[3]));
    mx = fmaxf(fmaxf(smx[0], smx[1]), fmaxf(smx[2], smx[3]));
    const float range = mx - mn;

    float bins[NB];
#pragma unroll
    for (int n = 0; n < NB; ++n) bins[n] = 0.f;

    const f4* cb = cosv4 + b * 1024;
#pragma unroll
    for (int j = 0; j < 4; ++j) {
        f4 sv = cb[j * 256 + threadIdx.x];
#pragma unroll
        for (int k = 0; k < 4; ++k) {
            const float s = sv[k];
#pragma unroll
            for (int n = 0; n < NB; ++n) {
                float lev = mn + ((float)n * range) / 15.0f;   // match ref order of ops
                float d = fabsf(s - lev);
                bins[n] += (d < 0.03125f) ? (1.0f - d) : 0.f;
            }
        }
    }
#pragma unroll
    for (int n = 0; n < NB; ++n) {
#pragma unroll
        for (int off = 32; off; off >>= 1) bins[n] += __shfl_down(bins[n], off, 64);
    }
    __shared__ float sb[4][NB];
    if (lane == 0) {
#pragma unroll
        for (int n = 0; n < NB; ++n) sb[wave][n] = bins[n];
    }
    __syncthreads();
    __shared__ float colsum[NB];
    if (threadIdx.x < NB) {
        const int n = threadIdx.x;
        colsum[n] = sb[0][n] + sb[1][n] + sb[2][n] + sb[3][n];
    }
    __syncthreads();
    float total = 0.f;
#pragma unroll
    for (int n = 0; n < NB; ++n) total += colsum[n];
    {
        const int i0 = threadIdx.x;
        out[b * (NB * 32) + i0]       = colsum[i0 >> 5] / total;
        out[b * (NB * 32) + i0 + 256] = colsum[(i0 + 256) >> 5] / total;
    }
}

extern "C" void kernel_launch(void* const* d_in, const int* in_sizes, int n_in,
                              void* d_out, int out_size, void* d_ws, size_t ws_size,
                              hipStream_t stream) {
    const float* x = (const float*)d_in[0];
    float* out = (float*)d_out;
    float* ws  = (float*)d_ws;

    float* g    = ws;                      // 16384 floats
    float* cosv = ws + 16384;              // 131072 floats
    float* pmin = ws + 16384 + 131072;     // 512
    float* pmax = pmin + 512;              // 512
    f4*    pd4  = (f4*)(pmax + 512);       // 512 blocks * 1024 f4 = 2M floats
    f4*    ps4  = pd4 + 524288;            // 2M floats

    k_main<<<512, 256, 0, stream>>>(x, g, pd4, ps4);
    k_reduce<<<512, 256, 0, stream>>>(g, pd4, ps4, (f4*)cosv, pmin, pmax);
    k_hist<<<32, 256, 0, stream>>>((const f4*)cosv, pmin, pmax, out);
}

// Round 8
// 74.167 us; speedup vs baseline: 1.3234x; 1.3234x over previous
//
#include <hip/hip_runtime.h>

typedef float f4 __attribute__((ext_vector_type(4)));

#define BB 32
#define CC 512
#define LL 4096
#define NB 16
#define EPSF 1e-8f

// ---------------- fused main kernel: barrier-free, ONE read of x ----------
// (R5 structure — best measured. Plain loads, no hot-loop barriers.)
// grid = 32 b x 16 chunks = 512 blocks (2/CU). Wave w owns channels
// c0+8w..8w+7; lane holds l = 256i + 4*lane + k.
__global__ __launch_bounds__(256, 2)
void k_main(const float* __restrict__ x, float* __restrict__ g,
            f4* __restrict__ pd4, f4* __restrict__ ps4) {
    __shared__ f4 ldsD[1024], ldsS[1024];    // 32 KB
    const int tid = threadIdx.x;
    const int w = tid >> 6, lane = tid & 63;
    const int b  = blockIdx.x >> 4;
    const int c0 = (blockIdx.x & 15) * 32;

    f4 dA[16], sA[16];
#pragma unroll
    for (int i = 0; i < 16; ++i) { dA[i] = (f4)0.f; sA[i] = (f4)0.f; }

    const f4* base = (const f4*)(x + ((size_t)b * CC + c0 + w * 8) * LL);
    for (int cc = 0; cc < 8; ++cc) {
        const f4* row = base + (size_t)cc * 1024;
        f4 v[16];
#pragma unroll
        for (int i = 0; i < 16; ++i) v[i] = row[i * 64 + lane];
        float s = 0.f;
#pragma unroll
        for (int i = 0; i < 16; ++i) s += (v[i][0] + v[i][1]) + (v[i][2] + v[i][3]);
#pragma unroll
        for (int off = 32; off; off >>= 1) s += __shfl_down(s, off, 64);
        s = __shfl(s, 0, 64);                // broadcast
        const float gv = s * (1.0f / LL);
        if (lane == 0) g[b * CC + c0 + w * 8 + cc] = gv;
#pragma unroll
        for (int i = 0; i < 16; ++i) {
#pragma unroll
            for (int k = 0; k < 4; ++k) {
                dA[i][k] = fmaf(v[i][k], gv, dA[i][k]);
                sA[i][k] = fmaf(v[i][k], v[i][k], sA[i][k]);
            }
        }
    }
    // 4-step wave combine (ascending w keeps c-summation order)
    for (int ww = 0; ww < 4; ++ww) {
        if (w == ww) {
#pragma unroll
            for (int i = 0; i < 16; ++i) {
                const int idx = i * 64 + lane;
                if (ww == 0) { ldsD[idx] = dA[i];  ldsS[idx] = sA[i]; }
                else         { ldsD[idx] += dA[i]; ldsS[idx] += sA[i]; }
            }
        }
        __syncthreads();
    }
#pragma unroll
    for (int j = 0; j < 4; ++j) {
        pd4[(size_t)blockIdx.x * 1024 + j * 256 + tid] = ldsD[j * 256 + tid];
        ps4[(size_t)blockIdx.x * 1024 + j * 256 + tid] = ldsS[j * 256 + tid];
    }
}

// ---------------- merged reduce + hist: 32 blocks x 1024 threads ----------
// Block b: fold 16 chunk-partials (L3-hot, just written) -> cos in regs
// (cos never materialized to HBM) -> per-b min/max -> release+arrive ->
// spin till all 32 blocks arrived -> global min/max -> bin own 4 values ->
// block reduce -> normalize -> write out. 32 blocks on 256 CUs are always
// co-resident, so the spin barrier cannot deadlock. counter is memset to 0
// on the stream before launch (deterministic across graph replays).
__global__ __launch_bounds__(1024, 1)
void k_rh(const float* __restrict__ g,
          const f4* __restrict__ pd4, const f4* __restrict__ ps4,
          float* __restrict__ pmin, float* __restrict__ pmax,
          unsigned* __restrict__ counter, float* __restrict__ out) {
    const int b = blockIdx.x;
    const int tid = threadIdx.x;            // 0..1023, one quad slot each
    const int w = tid >> 6, lane = tid & 63;

    // fold chunk partials (coalesced: 64 lanes x 16B = 1KB/wave/load)
    f4 pdv = (f4)0.f, psv = (f4)0.f;
    const size_t cb = (size_t)b * 16;
#pragma unroll
    for (int ch = 0; ch < 16; ++ch) {
        pdv += pd4[((cb + ch) << 10) + tid];
        psv += ps4[((cb + ch) << 10) + tid];
    }

    // gn per wave (redundant, L2-hot)
    const f4* g4p = (const f4*)(g + b * CC);
    f4 ga = g4p[lane], gb2 = g4p[64 + lane];
    float sq = 0.f;
#pragma unroll
    for (int k = 0; k < 4; ++k) sq = fmaf(ga[k], ga[k], fmaf(gb2[k], gb2[k], sq));
#pragma unroll
    for (int off = 32; off; off >>= 1) sq += __shfl_down(sq, off, 64);
    const float gn = sqrtf(__shfl(sq, 0, 64));

    f4 cs;
#pragma unroll
    for (int k = 0; k < 4; ++k)
        cs[k] = pdv[k] / fmaxf(sqrtf(psv[k]) * gn, EPSF);

    // per-b min/max
    float mn = fminf(fminf(cs[0], cs[1]), fminf(cs[2], cs[3]));
    float mx = fmaxf(fmaxf(cs[0], cs[1]), fmaxf(cs[2], cs[3]));
#pragma unroll
    for (int off = 32; off; off >>= 1) {
        mn = fminf(mn, __shfl_down(mn, off, 64));
        mx = fmaxf(mx, __shfl_down(mx, off, 64));
    }
    __shared__ float smn[16], smx[16];
    if (lane == 0) { smn[w] = mn; smx[w] = mx; }
    __syncthreads();
    if (tid == 0) {
        float bmn = smn[0], bmx = smx[0];
#pragma unroll
        for (int i = 1; i < 16; ++i) { bmn = fminf(bmn, smn[i]); bmx = fmaxf(bmx, smx[i]); }
        pmin[b] = bmn; pmax[b] = bmx;
        __threadfence();                     // release pmin/pmax
        atomicAdd(counter, 1u);              // arrive (device scope)
    }
    // spin until all 32 blocks arrived
    if (tid == 0) {
        while (__hip_atomic_load(counter, __ATOMIC_ACQUIRE, __HIP_MEMORY_SCOPE_AGENT) < 32u)
            __builtin_amdgcn_s_sleep(2);
    }
    __syncthreads();

    // global min/max over 32 blocks
    __shared__ float lmn[32], lmx[32];
    if (tid < 32) {
        lmn[tid] = __hip_atomic_load(&pmin[tid], __ATOMIC_RELAXED, __HIP_MEMORY_SCOPE_AGENT);
        lmx[tid] = __hip_atomic_load(&pmax[tid], __ATOMIC_RELAXED, __HIP_MEMORY_SCOPE_AGENT);
    }
    __syncthreads();
    float gmn = lmn[0], gmx = lmx[0];
#pragma unroll
    for (int i = 1; i < 32; ++i) { gmn = fminf(gmn, lmn[i]); gmx = fmaxf(gmx, lmx[i]); }
    const float range = gmx - gmn;

    // histogram of this thread's 4 cos values
    float bins[NB];
#pragma unroll
    for (int n = 0; n < NB; ++n) bins[n] = 0.f;
#pragma unroll
    for (int k = 0; k < 4; ++k) {
        const float s = cs[k];
#pragma unroll
        for (int n = 0; n < NB; ++n) {
            float lev = gmn + ((float)n * range) / 15.0f;   // match ref order of ops
            float d = fabsf(s - lev);
            bins[n] += (d < 0.03125f) ? (1.0f - d) : 0.f;
        }
    }
#pragma unroll
    for (int n = 0; n < NB; ++n) {
#pragma unroll
        for (int off = 32; off; off >>= 1) bins[n] += __shfl_down(bins[n], off, 64);
    }
    __shared__ float sb[16][NB];
    if (lane == 0) {
#pragma unroll
        for (int n = 0; n < NB; ++n) sb[w][n] = bins[n];
    }
    __syncthreads();
    __shared__ float colsum[NB];
    if (tid < NB) {
        float c = 0.f;
#pragma unroll
        for (int i = 0; i < 16; ++i) c += sb[i][tid];
        colsum[tid] = c;
    }
    __syncthreads();
    if (tid < NB * 32) {
        float total = 0.f;
#pragma unroll
        for (int n = 0; n < NB; ++n) total += colsum[n];
        out[b * (NB * 32) + tid] = colsum[tid >> 5] / total;
    }
}

extern "C" void kernel_launch(void* const* d_in, const int* in_sizes, int n_in,
                              void* d_out, int out_size, void* d_ws, size_t ws_size,
                              hipStream_t stream) {
    const float* x = (const float*)d_in[0];
    float* out = (float*)d_out;
    float* ws  = (float*)d_ws;

    float*    g       = ws;                       // 16384 floats
    float*    pmin    = ws + 16384;               // 32
    float*    pmax    = ws + 16384 + 64;          // 32
    unsigned* counter = (unsigned*)(ws + 16384 + 128);
    f4*       pd4     = (f4*)(ws + 16384 + 256);  // 512 blocks * 1024 f4
    f4*       ps4     = pd4 + 524288;             // 2M floats each

    hipMemsetAsync(counter, 0, sizeof(unsigned), stream);
    k_main<<<512, 256, 0, stream>>>(x, g, pd4, ps4);
    k_rh<<<32, 1024, 0, stream>>>(g, pd4, ps4, pmin, pmax, counter, out);
}